// Round 4
// baseline (697.399 us; speedup 1.0000x reference)
//
#include <hip/hip_runtime.h>

#define TEMP 0.0005f

typedef __attribute__((ext_vector_type(8))) short short8v;
typedef __attribute__((ext_vector_type(4))) float float4v;

static __device__ __forceinline__ unsigned short f2b(float f) {
  union { float f; unsigned int u; } x; x.f = f;
  unsigned int r = x.u + 0x7fffu + ((x.u >> 16) & 1u);
  return (unsigned short)(r >> 16);
}
static __device__ __forceinline__ float b2f(unsigned short h) {
  union { unsigned int u; float f; } x; x.u = ((unsigned int)h) << 16;
  return x.f;
}

// ---------------------------------------------------------------------------
// Weight convert+transpose: w[Cout][Cin][K] f32 -> wT[Cout][K][Cin] bf16
// ---------------------------------------------------------------------------
__global__ __launch_bounds__(256) void wcvt_k(
    const float* __restrict__ w, unsigned short* __restrict__ wT,
    int Cout, int Cin, int K)
{
  int o = blockIdx.x * 256 + threadIdx.x;
  if (o >= Cout * Cin * K) return;
  int co = o / (K * Cin);
  int r  = o - co * (K * Cin);
  int kh = r / Cin;
  int ci = r - kh * Cin;
  wT[o] = f2b(w[(co * Cin + ci) * K + kh]);
}

// ---------------------------------------------------------------------------
// mels [16][80][4000] f32 -> melsT [16][4000][80] bf16 (LDS transpose)
// ---------------------------------------------------------------------------
__global__ __launch_bounds__(256) void melscvt_k(
    const float* __restrict__ in, unsigned short* __restrict__ out)
{
  __shared__ float s[80][65];
  const int b  = blockIdx.y;
  const int t0 = blockIdx.x * 64;
  const int tid = threadIdx.x;
  for (int idx = tid; idx < 80 * 64; idx += 256) {
    int c = idx >> 6, tl = idx & 63;
    int t = t0 + tl;
    s[c][tl] = (t < 4000) ? in[((size_t)b * 80 + c) * 4000 + t] : 0.f;
  }
  __syncthreads();
  for (int idx = tid; idx < 64 * 80; idx += 256) {
    int tl = idx / 80, c = idx - tl * 80;
    int t = t0 + tl;
    if (t < 4000) out[((size_t)b * 4000 + t) * 80 + c] = f2b(s[c][tl]);
  }
}

// ---------------------------------------------------------------------------
// Embedding gather: x[bs][e] = bf16(emb[ph[bs]][e]), one block per (b,s)
// ---------------------------------------------------------------------------
__global__ __launch_bounds__(256) void gather_k(
    const int* __restrict__ ph, const float* __restrict__ emb,
    unsigned short* __restrict__ x)
{
  const int bs = blockIdx.x;
  const int p = ph[bs];
  const float* e = emb + (size_t)p * 512;
  unsigned short* o = x + (size_t)bs * 512;
  int i = threadIdx.x * 2;
  float2 v = *(const float2*)&e[i];
  unsigned int pk = (unsigned)f2b(v.x) | ((unsigned)f2b(v.y) << 16);
  *(unsigned int*)&o[i] = pk;
}

// ---------------------------------------------------------------------------
// MFMA conv1d (SAME, stride 1), bf16 in/out, fp32 accum.
// in:  [B][T][Cin] bf16.  wT: [Cout][K][Cin] bf16.  out: [B][T][Cout] bf16.
// Block: 256 thr = 4 waves. Tile: 128co x 128t; each wave 64co x 64t (4x4 acc).
// Staging/fragments/epilogue use the round-2-verified mapping.
// ---------------------------------------------------------------------------
template<int K, bool RELU>
__global__ __launch_bounds__(256) void conv_mfma(
    const unsigned short* __restrict__ in,
    const unsigned short* __restrict__ wT,
    const float* __restrict__ bias,
    unsigned short* __restrict__ out,
    int Cin, int Cout, int T)
{
  constexpr int P   = K / 2;
  constexpr int BT  = 128;
  constexpr int BC  = 128;
  constexpr int TW  = BT + K - 1;
  constexpr int WR  = K * 32 + 8;

  __shared__ unsigned short in_s[TW][40];   // [tloc][ci] bf16, 80B rows
  __shared__ unsigned short w_s[BC][WR];    // [co][kh*32+ci]

  const int b    = blockIdx.z;
  const int t0   = blockIdx.x * BT;
  const int co0  = blockIdx.y * BC;
  const int tid  = threadIdx.x;
  const int lane = tid & 63;
  const int wv   = tid >> 6;
  const int wco  = (wv & 1) << 6;   // 0,64
  const int wt   = (wv >> 1) << 6;  // 0,64
  const int l15  = lane & 15;
  const int lq   = lane >> 4;       // 0..3

  const unsigned short* inb = in + (size_t)b * T * Cin;
  const size_t wrow = (size_t)K * Cin;

  float4v acc[4][4];
  #pragma unroll
  for (int m = 0; m < 4; ++m)
    #pragma unroll
    for (int n = 0; n < 4; ++n) { float4v z = {0.f,0.f,0.f,0.f}; acc[m][n] = z; }

  for (int ci0 = 0; ci0 < Cin; ci0 += 32) {
    // stage input tile: TW rows x 32 ci, 16B granules, zero-padded
    for (int g = tid; g < TW * 4; g += 256) {
      int tl = g >> 2, q = g & 3;
      int gt = t0 + tl - P;
      int ci = ci0 + q * 8;
      short8v v = {};
      if (gt >= 0 && gt < T && ci < Cin)
        v = *(const short8v*)&inb[(size_t)gt * Cin + ci];
      *(short8v*)&in_s[tl][q * 8] = v;
    }
    // stage weights: BC rows x K*32
    for (int g = tid; g < BC * K * 4; g += 256) {
      int co = g / (K * 4);
      int r  = g - co * (K * 4);
      int kh = r >> 2, q = r & 3;
      int ci = ci0 + q * 8;
      short8v v = {};
      if (co0 + co < Cout && ci < Cin)
        v = *(const short8v*)&wT[(size_t)(co0 + co) * wrow + (size_t)kh * Cin + ci];
      *(short8v*)&w_s[co][kh * 32 + q * 8] = v;
    }
    __syncthreads();

    #pragma unroll
    for (int kh = 0; kh < K; ++kh) {
      short8v a0 = *(const short8v*)&w_s[wco      + l15][kh * 32 + lq * 8];
      short8v a1 = *(const short8v*)&w_s[wco + 16 + l15][kh * 32 + lq * 8];
      short8v a2 = *(const short8v*)&w_s[wco + 32 + l15][kh * 32 + lq * 8];
      short8v a3 = *(const short8v*)&w_s[wco + 48 + l15][kh * 32 + lq * 8];
      short8v b0 = *(const short8v*)&in_s[wt      + l15 + kh][lq * 8];
      short8v b1 = *(const short8v*)&in_s[wt + 16 + l15 + kh][lq * 8];
      short8v b2 = *(const short8v*)&in_s[wt + 32 + l15 + kh][lq * 8];
      short8v b3 = *(const short8v*)&in_s[wt + 48 + l15 + kh][lq * 8];
      acc[0][0] = __builtin_amdgcn_mfma_f32_16x16x32_bf16(a0, b0, acc[0][0], 0, 0, 0);
      acc[0][1] = __builtin_amdgcn_mfma_f32_16x16x32_bf16(a0, b1, acc[0][1], 0, 0, 0);
      acc[0][2] = __builtin_amdgcn_mfma_f32_16x16x32_bf16(a0, b2, acc[0][2], 0, 0, 0);
      acc[0][3] = __builtin_amdgcn_mfma_f32_16x16x32_bf16(a0, b3, acc[0][3], 0, 0, 0);
      acc[1][0] = __builtin_amdgcn_mfma_f32_16x16x32_bf16(a1, b0, acc[1][0], 0, 0, 0);
      acc[1][1] = __builtin_amdgcn_mfma_f32_16x16x32_bf16(a1, b1, acc[1][1], 0, 0, 0);
      acc[1][2] = __builtin_amdgcn_mfma_f32_16x16x32_bf16(a1, b2, acc[1][2], 0, 0, 0);
      acc[1][3] = __builtin_amdgcn_mfma_f32_16x16x32_bf16(a1, b3, acc[1][3], 0, 0, 0);
      acc[2][0] = __builtin_amdgcn_mfma_f32_16x16x32_bf16(a2, b0, acc[2][0], 0, 0, 0);
      acc[2][1] = __builtin_amdgcn_mfma_f32_16x16x32_bf16(a2, b1, acc[2][1], 0, 0, 0);
      acc[2][2] = __builtin_amdgcn_mfma_f32_16x16x32_bf16(a2, b2, acc[2][2], 0, 0, 0);
      acc[2][3] = __builtin_amdgcn_mfma_f32_16x16x32_bf16(a2, b3, acc[2][3], 0, 0, 0);
      acc[3][0] = __builtin_amdgcn_mfma_f32_16x16x32_bf16(a3, b0, acc[3][0], 0, 0, 0);
      acc[3][1] = __builtin_amdgcn_mfma_f32_16x16x32_bf16(a3, b1, acc[3][1], 0, 0, 0);
      acc[3][2] = __builtin_amdgcn_mfma_f32_16x16x32_bf16(a3, b2, acc[3][2], 0, 0, 0);
      acc[3][3] = __builtin_amdgcn_mfma_f32_16x16x32_bf16(a3, b3, acc[3][3], 0, 0, 0);
    }
    __syncthreads();
  }

  // epilogue: D col = lane&15 -> t, row = (lane>>4)*4 + r -> co
  #pragma unroll
  for (int m = 0; m < 4; ++m) {
    int co = co0 + wco + m * 16 + (lq << 2);
    if (co >= Cout) continue;
    float4v bv = *(const float4v*)&bias[co];
    #pragma unroll
    for (int n = 0; n < 4; ++n) {
      int t = t0 + wt + n * 16 + l15;
      if (t >= T) continue;
      float v0 = acc[m][n][0] + bv[0];
      float v1 = acc[m][n][1] + bv[1];
      float v2 = acc[m][n][2] + bv[2];
      float v3 = acc[m][n][3] + bv[3];
      if (RELU) {
        v0 = fmaxf(v0, 0.f); v1 = fmaxf(v1, 0.f);
        v2 = fmaxf(v2, 0.f); v3 = fmaxf(v3, 0.f);
      }
      unsigned long long pk =
          (unsigned long long)((unsigned)f2b(v0) | ((unsigned)f2b(v1) << 16)) |
          ((unsigned long long)((unsigned)f2b(v2) | ((unsigned)f2b(v3) << 16)) << 32);
      *(unsigned long long*)&out[((size_t)b * T + t) * Cout + co] = pk;
    }
  }
}

// ---------------------------------------------------------------------------
// Row sum of squares: o[row] = sum_c x[row][c]^2, rows of 80 bf16
// ---------------------------------------------------------------------------
__global__ __launch_bounds__(256) void sumsq_k(
    const unsigned short* __restrict__ x, float* __restrict__ o, int N)
{
  int idx = blockIdx.x * 256 + threadIdx.x;
  if (idx >= N) return;
  const unsigned short* r = x + (size_t)idx * 80;
  float s = 0.f;
  #pragma unroll
  for (int g = 0; g < 10; ++g) {
    short8v v = *(const short8v*)&r[g * 8];
    #pragma unroll
    for (int j = 0; j < 8; ++j) { float f = b2f((unsigned short)v[j]); s += f * f; }
  }
  o[idx] = s;
}

// ---------------------------------------------------------------------------
// attention[b][t][s] = -TEMP*(q2[t]+k2[s]-2*qk), qk via MFMA over C=80 (pad 96)
// ---------------------------------------------------------------------------
__global__ __launch_bounds__(256) void attn_mfma(
    const unsigned short* __restrict__ q, const unsigned short* __restrict__ k,
    const float* __restrict__ q2, const float* __restrict__ k2,
    float* __restrict__ out)
{
  __shared__ unsigned short q_s[64][104];
  __shared__ unsigned short k_s[64][104];
  const int b  = blockIdx.z;
  const int t0 = blockIdx.y * 64;
  const int s0 = blockIdx.x * 64;
  const int tid  = threadIdx.x;
  const int lane = tid & 63;
  const int wv   = tid >> 6;
  const int wt   = (wv & 1) << 5;
  const int ws   = (wv >> 1) << 5;
  const int l15  = lane & 15;
  const int lq   = lane >> 4;

  for (int g = tid; g < 64 * 12; g += 256) {
    int row = g / 12, c = (g - row * 12) * 8;
    short8v vq = {}, vk = {};
    int t = t0 + row;
    if (c < 80) {
      if (t < 4000) vq = *(const short8v*)&q[((size_t)b * 4000 + t) * 80 + c];
      vk = *(const short8v*)&k[((size_t)b * 512 + s0 + row) * 80 + c];
    }
    *(short8v*)&q_s[row][c] = vq;
    *(short8v*)&k_s[row][c] = vk;
  }
  __syncthreads();

  float4v acc[2][2];
  #pragma unroll
  for (int m = 0; m < 2; ++m)
    #pragma unroll
    for (int n = 0; n < 2; ++n) { float4v z = {0.f,0.f,0.f,0.f}; acc[m][n] = z; }

  #pragma unroll
  for (int ks = 0; ks < 3; ++ks) {
    short8v a0 = *(const short8v*)&q_s[wt      + l15][ks * 32 + lq * 8];
    short8v a1 = *(const short8v*)&q_s[wt + 16 + l15][ks * 32 + lq * 8];
    short8v b0 = *(const short8v*)&k_s[ws      + l15][ks * 32 + lq * 8];
    short8v b1 = *(const short8v*)&k_s[ws + 16 + l15][ks * 32 + lq * 8];
    acc[0][0] = __builtin_amdgcn_mfma_f32_16x16x32_bf16(a0, b0, acc[0][0], 0, 0, 0);
    acc[0][1] = __builtin_amdgcn_mfma_f32_16x16x32_bf16(a0, b1, acc[0][1], 0, 0, 0);
    acc[1][0] = __builtin_amdgcn_mfma_f32_16x16x32_bf16(a1, b0, acc[1][0], 0, 0, 0);
    acc[1][1] = __builtin_amdgcn_mfma_f32_16x16x32_bf16(a1, b1, acc[1][1], 0, 0, 0);
  }

  #pragma unroll
  for (int m = 0; m < 2; ++m) {
    #pragma unroll
    for (int r = 0; r < 4; ++r) {
      int t = t0 + wt + m * 16 + lq * 4 + r;
      if (t >= 4000) continue;
      float q2v = q2[b * 4000 + t];
      #pragma unroll
      for (int n = 0; n < 2; ++n) {
        int s = s0 + ws + n * 16 + l15;
        float v = -TEMP * (q2v + k2[b * 512 + s] - 2.f * acc[m][n][r]);
        out[((size_t)b * 4000 + t) * 512 + s] = v;
      }
    }
  }
}

// ---------------------------------------------------------------------------
extern "C" void kernel_launch(void* const* d_in, const int* in_sizes, int n_in,
                              void* d_out, int out_size, void* d_ws, size_t ws_size,
                              hipStream_t stream)
{
  const float* mels = (const float*)d_in[0];
  const int*   ph   = (const int*)  d_in[1];
  const float* emb  = (const float*)d_in[2];
  const float* tw1  = (const float*)d_in[3];
  const float* tb1  = (const float*)d_in[4];
  const float* tw2  = (const float*)d_in[5];
  const float* tb2  = (const float*)d_in[6];
  const float* tw3  = (const float*)d_in[7];
  const float* tb3  = (const float*)d_in[8];
  const float* ow1  = (const float*)d_in[9];
  const float* ob1  = (const float*)d_in[10];
  const float* ow2  = (const float*)d_in[11];
  const float* ob2  = (const float*)d_in[12];
  const float* mw1  = (const float*)d_in[13];
  const float* mb1  = (const float*)d_in[14];
  const float* mw2  = (const float*)d_in[15];
  const float* mb2  = (const float*)d_in[16];
  const float* mw3  = (const float*)d_in[17];
  const float* mb3  = (const float*)d_in[18];
  float* out = (float*)d_out;

  // ---- workspace carve (identical to round-2-verified layout) ----
  char* base = (char*)d_ws;
  unsigned short* wTtw1 = (unsigned short*)base; base += 512 * 2560 * 2;
  unsigned short* wTtw2 = (unsigned short*)base; base += 512 * 2560 * 2;
  unsigned short* wTtw3 = (unsigned short*)base; base += 512 * 2560 * 2;
  unsigned short* wTow1 = (unsigned short*)base; base += 1024 * 1536 * 2;
  unsigned short* wTmw1 = (unsigned short*)base; base += 256 * 240 * 2;
  unsigned short* wTmw2 = (unsigned short*)base; base += 128 * 768 * 2;
  unsigned short* wTmw3 = (unsigned short*)base; base += 80 * 128 * 2;
  unsigned short* wTow2 = (unsigned short*)base; base += 80 * 1024 * 2;
  unsigned short* melsT = (unsigned short*)base; base += 16 * 4000 * 80 * 2;
  unsigned short* actA  = (unsigned short*)base; base += 16 * 4000 * 256 * 2;
  unsigned short* actB  = (unsigned short*)base; base += 16 * 4000 * 128 * 2;
  unsigned short* qb    = (unsigned short*)base; base += 16 * 4000 * 80 * 2;
  unsigned short* x0    = (unsigned short*)base; base += 16 * 512 * 512 * 2;
  unsigned short* x1    = (unsigned short*)base; base += 16 * 512 * 512 * 2;
  unsigned short* yb    = (unsigned short*)base; base += 16 * 512 * 1024 * 2;
  unsigned short* kb    = (unsigned short*)base; base += 16 * 512 * 80 * 2;
  float* q2v = (float*)base; base += 64000 * 4;
  float* k2v = (float*)base; base += 8192 * 4;

  // ---- weight convert/transpose (bf16) ----
  wcvt_k<<<5120, 256, 0, stream>>>(tw1, wTtw1, 512, 512, 5);
  wcvt_k<<<5120, 256, 0, stream>>>(tw2, wTtw2, 512, 512, 5);
  wcvt_k<<<5120, 256, 0, stream>>>(tw3, wTtw3, 512, 512, 5);
  wcvt_k<<<6144, 256, 0, stream>>>(ow1, wTow1, 1024, 512, 3);
  wcvt_k<<<240, 256, 0, stream>>>(mw1, wTmw1, 256, 80, 3);
  wcvt_k<<<384, 256, 0, stream>>>(mw2, wTmw2, 128, 256, 3);
  wcvt_k<<<40, 256, 0, stream>>>(mw3, wTmw3, 80, 128, 1);
  wcvt_k<<<320, 256, 0, stream>>>(ow2, wTow2, 80, 1024, 1);

  // ---- input conversions ----
  melscvt_k<<<dim3(63, 16), 256, 0, stream>>>(mels, melsT);
  gather_k<<<8192, 256, 0, stream>>>(ph, emb, x0);

  // ---- q path (T=4000), 128co x 128t tiles ----
  conv_mfma<3, true ><<<dim3(32, 2, 16), 256, 0, stream>>>(melsT, wTmw1, mb1, actA,  80, 256, 4000);
  conv_mfma<3, true ><<<dim3(32, 1, 16), 256, 0, stream>>>(actA,  wTmw2, mb2, actB, 256, 128, 4000);
  conv_mfma<1, false><<<dim3(32, 1, 16), 256, 0, stream>>>(actB,  wTmw3, mb3, qb,   128,  80, 4000);

  // ---- k path (T=512) ----
  conv_mfma<5, true ><<<dim3(4, 4, 16), 256, 0, stream>>>(x0, wTtw1, tb1, x1,  512,  512, 512);
  conv_mfma<5, true ><<<dim3(4, 4, 16), 256, 0, stream>>>(x1, wTtw2, tb2, x0,  512,  512, 512);
  conv_mfma<5, true ><<<dim3(4, 4, 16), 256, 0, stream>>>(x0, wTtw3, tb3, x1,  512,  512, 512);
  conv_mfma<3, true ><<<dim3(4, 8, 16), 256, 0, stream>>>(x1, wTow1, ob1, yb,  512, 1024, 512);
  conv_mfma<1, false><<<dim3(4, 1, 16), 256, 0, stream>>>(yb, wTow2, ob2, kb, 1024,   80, 512);

  // ---- reductions + fused distance epilogue ----
  sumsq_k<<<250, 256, 0, stream>>>(qb, q2v, 64000);
  sumsq_k<<<32, 256, 0, stream>>>(kb, k2v, 8192);
  attn_mfma<<<dim3(8, 63, 16), 256, 0, stream>>>(qb, kb, q2v, k2v, out);
}

// Round 5
// 559.979 us; speedup vs baseline: 1.2454x; 1.2454x over previous
//
#include <hip/hip_runtime.h>

#define TEMP 0.0005f

typedef __attribute__((ext_vector_type(8))) short short8v;
typedef __attribute__((ext_vector_type(4))) float float4v;

static __device__ __forceinline__ unsigned short f2b(float f) {
  union { float f; unsigned int u; } x; x.f = f;
  unsigned int r = x.u + 0x7fffu + ((x.u >> 16) & 1u);
  return (unsigned short)(r >> 16);
}
static __device__ __forceinline__ float b2f(unsigned short h) {
  union { unsigned int u; float f; } x; x.u = ((unsigned int)h) << 16;
  return x.f;
}

// ---------------------------------------------------------------------------
// Weight convert+transpose: w[Cout][Cin][K] f32 -> wT[Cout][K][Cin] bf16
// ---------------------------------------------------------------------------
__global__ __launch_bounds__(256) void wcvt_k(
    const float* __restrict__ w, unsigned short* __restrict__ wT,
    int Cout, int Cin, int K)
{
  int o = blockIdx.x * 256 + threadIdx.x;
  if (o >= Cout * Cin * K) return;
  int co = o / (K * Cin);
  int r  = o - co * (K * Cin);
  int kh = r / Cin;
  int ci = r - kh * Cin;
  wT[o] = f2b(w[(co * Cin + ci) * K + kh]);
}

// ---------------------------------------------------------------------------
// mels [16][80][4000] f32 -> melsT [16][4000][80] bf16 (LDS transpose)
// ---------------------------------------------------------------------------
__global__ __launch_bounds__(256) void melscvt_k(
    const float* __restrict__ in, unsigned short* __restrict__ out)
{
  __shared__ float s[80][65];
  const int b  = blockIdx.y;
  const int t0 = blockIdx.x * 64;
  const int tid = threadIdx.x;
  for (int idx = tid; idx < 80 * 64; idx += 256) {
    int c = idx >> 6, tl = idx & 63;
    int t = t0 + tl;
    s[c][tl] = (t < 4000) ? in[((size_t)b * 80 + c) * 4000 + t] : 0.f;
  }
  __syncthreads();
  for (int idx = tid; idx < 64 * 80; idx += 256) {
    int tl = idx / 80, c = idx - tl * 80;
    int t = t0 + tl;
    if (t < 4000) out[((size_t)b * 4000 + t) * 80 + c] = f2b(s[c][tl]);
  }
}

// ---------------------------------------------------------------------------
// Embedding gather: x[bs][e] = bf16(emb[ph[bs]][e]), one block per (b,s)
// ---------------------------------------------------------------------------
__global__ __launch_bounds__(256) void gather_k(
    const int* __restrict__ ph, const float* __restrict__ emb,
    unsigned short* __restrict__ x)
{
  const int bs = blockIdx.x;
  const int p = ph[bs];
  const float* e = emb + (size_t)p * 512;
  unsigned short* o = x + (size_t)bs * 512;
  int i = threadIdx.x * 2;
  float2 v = *(const float2*)&e[i];
  unsigned int pk = (unsigned)f2b(v.x) | ((unsigned)f2b(v.y) << 16);
  *(unsigned int*)&o[i] = pk;
}

// ---------------------------------------------------------------------------
// MFMA conv1d (SAME, stride 1), bf16 in/out, fp32 accum.
// in:  [B][T][Cin] bf16.  wT: [Cout][K][Cin] bf16.  out: [B][T][Cout] bf16.
// Block: 128 thr = 2 waves. Tile: 64co x 128t; each wave 64co x 64t (4x4 acc).
// Reg-staged 2-phase pipeline: load chunk c+1 to regs BEFORE compute(c),
// ds_write to the other LDS buffer AFTER compute, one barrier per chunk.
// Staging addresses / fragment maps / epilogue = round-2-verified math.
// ---------------------------------------------------------------------------
template<int K, bool RELU>
__global__ __launch_bounds__(128) void conv_mfma(
    const unsigned short* __restrict__ in,
    const unsigned short* __restrict__ wT,
    const float* __restrict__ bias,
    unsigned short* __restrict__ out,
    int Cin, int Cout, int T)
{
  constexpr int P   = K / 2;
  constexpr int BT  = 128;
  constexpr int TW  = BT + K - 1;            // 132 / 130 / 128
  constexpr int WR  = K * 32 + 8;            // padded row (verified)
  constexpr int NI  = (TW * 4 + 127) / 128;  // input granules per thread
  constexpr int NW  = 2 * K;                 // weight granules per thread

  __shared__ unsigned short in_s[2][TW][40];   // [buf][tloc][ci], 80B rows
  __shared__ unsigned short w_s[2][64][WR];    // [buf][co][kh*32+ci]

  const int b    = blockIdx.z;
  const int t0   = blockIdx.x * BT;
  const int co0  = blockIdx.y * 64;
  const int tid  = threadIdx.x;
  const int lane = tid & 63;
  const int wv   = tid >> 6;        // 0,1
  const int wt   = wv << 6;         // wave t-offset 0,64
  const int l15  = lane & 15;
  const int lq   = lane >> 4;       // 0..3

  const unsigned short* inb = in + (size_t)b * T * Cin;
  const size_t wrow = (size_t)K * Cin;

  float4v acc[4][4];
  #pragma unroll
  for (int m = 0; m < 4; ++m)
    #pragma unroll
    for (int n = 0; n < 4; ++n) { float4v z = {0.f,0.f,0.f,0.f}; acc[m][n] = z; }

  short8v rin[NI];
  short8v rw[NW];

  // global -> regs (chunk ci0); same guards/addresses as verified staging
  auto load_chunk = [&](int ci0) {
    #pragma unroll
    for (int i = 0; i < NI; ++i) {
      int g = tid + 128 * i;
      short8v v = {};
      if (g < TW * 4) {
        int tl = g >> 2, q = g & 3;
        int gt = t0 + tl - P;
        int ci = ci0 + q * 8;
        if (gt >= 0 && gt < T && ci < Cin)
          v = *(const short8v*)&inb[(size_t)gt * Cin + ci];
      }
      rin[i] = v;
    }
    #pragma unroll
    for (int j = 0; j < NW; ++j) {
      int h = tid + 128 * j;        // h < 256*K = 64 * 4K exactly
      int co = h & 63;              // lanes sweep all 64 co -> uniform banks
      int rq = h >> 6;              // 0..4K-1
      int kh = rq >> 2, q = rq & 3;
      int ci = ci0 + q * 8;
      short8v v = {};
      if (co0 + co < Cout && ci < Cin)
        v = *(const short8v*)&wT[(size_t)(co0 + co) * wrow + (size_t)kh * Cin + ci];
      rw[j] = v;
    }
  };

  // regs -> LDS buf
  auto write_chunk = [&](int buf) {
    #pragma unroll
    for (int i = 0; i < NI; ++i) {
      int g = tid + 128 * i;
      if (g < TW * 4) {
        int tl = g >> 2, q = g & 3;
        *(short8v*)&in_s[buf][tl][q * 8] = rin[i];
      }
    }
    #pragma unroll
    for (int j = 0; j < NW; ++j) {
      int h = tid + 128 * j;
      int co = h & 63;
      int rq = h >> 6;
      int kh = rq >> 2, q = rq & 3;
      *(short8v*)&w_s[buf][co][kh * 32 + q * 8] = rw[j];
    }
  };

  auto compute = [&](int buf) {
    #pragma unroll
    for (int kh = 0; kh < K; ++kh) {
      short8v a0 = *(const short8v*)&w_s[buf][     l15][kh * 32 + lq * 8];
      short8v a1 = *(const short8v*)&w_s[buf][16 + l15][kh * 32 + lq * 8];
      short8v a2 = *(const short8v*)&w_s[buf][32 + l15][kh * 32 + lq * 8];
      short8v a3 = *(const short8v*)&w_s[buf][48 + l15][kh * 32 + lq * 8];
      short8v b0 = *(const short8v*)&in_s[buf][wt      + l15 + kh][lq * 8];
      short8v b1 = *(const short8v*)&in_s[buf][wt + 16 + l15 + kh][lq * 8];
      short8v b2 = *(const short8v*)&in_s[buf][wt + 32 + l15 + kh][lq * 8];
      short8v b3 = *(const short8v*)&in_s[buf][wt + 48 + l15 + kh][lq * 8];
      acc[0][0] = __builtin_amdgcn_mfma_f32_16x16x32_bf16(a0, b0, acc[0][0], 0, 0, 0);
      acc[0][1] = __builtin_amdgcn_mfma_f32_16x16x32_bf16(a0, b1, acc[0][1], 0, 0, 0);
      acc[0][2] = __builtin_amdgcn_mfma_f32_16x16x32_bf16(a0, b2, acc[0][2], 0, 0, 0);
      acc[0][3] = __builtin_amdgcn_mfma_f32_16x16x32_bf16(a0, b3, acc[0][3], 0, 0, 0);
      acc[1][0] = __builtin_amdgcn_mfma_f32_16x16x32_bf16(a1, b0, acc[1][0], 0, 0, 0);
      acc[1][1] = __builtin_amdgcn_mfma_f32_16x16x32_bf16(a1, b1, acc[1][1], 0, 0, 0);
      acc[1][2] = __builtin_amdgcn_mfma_f32_16x16x32_bf16(a1, b2, acc[1][2], 0, 0, 0);
      acc[1][3] = __builtin_amdgcn_mfma_f32_16x16x32_bf16(a1, b3, acc[1][3], 0, 0, 0);
      acc[2][0] = __builtin_amdgcn_mfma_f32_16x16x32_bf16(a2, b0, acc[2][0], 0, 0, 0);
      acc[2][1] = __builtin_amdgcn_mfma_f32_16x16x32_bf16(a2, b1, acc[2][1], 0, 0, 0);
      acc[2][2] = __builtin_amdgcn_mfma_f32_16x16x32_bf16(a2, b2, acc[2][2], 0, 0, 0);
      acc[2][3] = __builtin_amdgcn_mfma_f32_16x16x32_bf16(a2, b3, acc[2][3], 0, 0, 0);
      acc[3][0] = __builtin_amdgcn_mfma_f32_16x16x32_bf16(a3, b0, acc[3][0], 0, 0, 0);
      acc[3][1] = __builtin_amdgcn_mfma_f32_16x16x32_bf16(a3, b1, acc[3][1], 0, 0, 0);
      acc[3][2] = __builtin_amdgcn_mfma_f32_16x16x32_bf16(a3, b2, acc[3][2], 0, 0, 0);
      acc[3][3] = __builtin_amdgcn_mfma_f32_16x16x32_bf16(a3, b3, acc[3][3], 0, 0, 0);
    }
  };

  const int NC = (Cin + 31) >> 5;
  load_chunk(0);
  write_chunk(0);
  __syncthreads();
  int cur = 0;
  for (int c = 0; c < NC; ++c) {
    if (c + 1 < NC) load_chunk((c + 1) * 32);   // issue early (hidden by MFMA)
    compute(cur);
    if (c + 1 < NC) write_chunk(cur ^ 1);       // write late, other buffer
    __syncthreads();
    cur ^= 1;
  }

  // epilogue: D col = lane&15 -> t, row = (lane>>4)*4 + r -> co  (verified)
  #pragma unroll
  for (int m = 0; m < 4; ++m) {
    int co = co0 + m * 16 + (lq << 2);
    if (co >= Cout) continue;
    float4v bv = *(const float4v*)&bias[co];
    #pragma unroll
    for (int n = 0; n < 4; ++n) {
      int t = t0 + wt + n * 16 + l15;
      if (t >= T) continue;
      float v0 = acc[m][n][0] + bv[0];
      float v1 = acc[m][n][1] + bv[1];
      float v2 = acc[m][n][2] + bv[2];
      float v3 = acc[m][n][3] + bv[3];
      if (RELU) {
        v0 = fmaxf(v0, 0.f); v1 = fmaxf(v1, 0.f);
        v2 = fmaxf(v2, 0.f); v3 = fmaxf(v3, 0.f);
      }
      unsigned long long pk =
          (unsigned long long)((unsigned)f2b(v0) | ((unsigned)f2b(v1) << 16)) |
          ((unsigned long long)((unsigned)f2b(v2) | ((unsigned)f2b(v3) << 16)) << 32);
      *(unsigned long long*)&out[((size_t)b * T + t) * Cout + co] = pk;
    }
  }
}

// ---------------------------------------------------------------------------
// Row sum of squares: o[row] = sum_c x[row][c]^2, rows of 80 bf16
// ---------------------------------------------------------------------------
__global__ __launch_bounds__(256) void sumsq_k(
    const unsigned short* __restrict__ x, float* __restrict__ o, int N)
{
  int idx = blockIdx.x * 256 + threadIdx.x;
  if (idx >= N) return;
  const unsigned short* r = x + (size_t)idx * 80;
  float s = 0.f;
  #pragma unroll
  for (int g = 0; g < 10; ++g) {
    short8v v = *(const short8v*)&r[g * 8];
    #pragma unroll
    for (int j = 0; j < 8; ++j) { float f = b2f((unsigned short)v[j]); s += f * f; }
  }
  o[idx] = s;
}

// ---------------------------------------------------------------------------
// attention[b][t][s] = -TEMP*(q2[t]+k2[s]-2*qk), qk via MFMA over C=80 (pad 96)
// ---------------------------------------------------------------------------
__global__ __launch_bounds__(256) void attn_mfma(
    const unsigned short* __restrict__ q, const unsigned short* __restrict__ k,
    const float* __restrict__ q2, const float* __restrict__ k2,
    float* __restrict__ out)
{
  __shared__ unsigned short q_s[64][104];
  __shared__ unsigned short k_s[64][104];
  const int b  = blockIdx.z;
  const int t0 = blockIdx.y * 64;
  const int s0 = blockIdx.x * 64;
  const int tid  = threadIdx.x;
  const int lane = tid & 63;
  const int wv   = tid >> 6;
  const int wt   = (wv & 1) << 5;
  const int ws   = (wv >> 1) << 5;
  const int l15  = lane & 15;
  const int lq   = lane >> 4;

  for (int g = tid; g < 64 * 12; g += 256) {
    int row = g / 12, c = (g - row * 12) * 8;
    short8v vq = {}, vk = {};
    int t = t0 + row;
    if (c < 80) {
      if (t < 4000) vq = *(const short8v*)&q[((size_t)b * 4000 + t) * 80 + c];
      vk = *(const short8v*)&k[((size_t)b * 512 + s0 + row) * 80 + c];
    }
    *(short8v*)&q_s[row][c] = vq;
    *(short8v*)&k_s[row][c] = vk;
  }
  __syncthreads();

  float4v acc[2][2];
  #pragma unroll
  for (int m = 0; m < 2; ++m)
    #pragma unroll
    for (int n = 0; n < 2; ++n) { float4v z = {0.f,0.f,0.f,0.f}; acc[m][n] = z; }

  #pragma unroll
  for (int ks = 0; ks < 3; ++ks) {
    short8v a0 = *(const short8v*)&q_s[wt      + l15][ks * 32 + lq * 8];
    short8v a1 = *(const short8v*)&q_s[wt + 16 + l15][ks * 32 + lq * 8];
    short8v b0 = *(const short8v*)&k_s[ws      + l15][ks * 32 + lq * 8];
    short8v b1 = *(const short8v*)&k_s[ws + 16 + l15][ks * 32 + lq * 8];
    acc[0][0] = __builtin_amdgcn_mfma_f32_16x16x32_bf16(a0, b0, acc[0][0], 0, 0, 0);
    acc[0][1] = __builtin_amdgcn_mfma_f32_16x16x32_bf16(a0, b1, acc[0][1], 0, 0, 0);
    acc[1][0] = __builtin_amdgcn_mfma_f32_16x16x32_bf16(a1, b0, acc[1][0], 0, 0, 0);
    acc[1][1] = __builtin_amdgcn_mfma_f32_16x16x32_bf16(a1, b1, acc[1][1], 0, 0, 0);
  }

  #pragma unroll
  for (int m = 0; m < 2; ++m) {
    #pragma unroll
    for (int r = 0; r < 4; ++r) {
      int t = t0 + wt + m * 16 + lq * 4 + r;
      if (t >= 4000) continue;
      float q2v = q2[b * 4000 + t];
      #pragma unroll
      for (int n = 0; n < 2; ++n) {
        int s = s0 + ws + n * 16 + l15;
        float v = -TEMP * (q2v + k2[b * 512 + s] - 2.f * acc[m][n][r]);
        out[((size_t)b * 4000 + t) * 512 + s] = v;
      }
    }
  }
}

// ---------------------------------------------------------------------------
extern "C" void kernel_launch(void* const* d_in, const int* in_sizes, int n_in,
                              void* d_out, int out_size, void* d_ws, size_t ws_size,
                              hipStream_t stream)
{
  const float* mels = (const float*)d_in[0];
  const int*   ph   = (const int*)  d_in[1];
  const float* emb  = (const float*)d_in[2];
  const float* tw1  = (const float*)d_in[3];
  const float* tb1  = (const float*)d_in[4];
  const float* tw2  = (const float*)d_in[5];
  const float* tb2  = (const float*)d_in[6];
  const float* tw3  = (const float*)d_in[7];
  const float* tb3  = (const float*)d_in[8];
  const float* ow1  = (const float*)d_in[9];
  const float* ob1  = (const float*)d_in[10];
  const float* ow2  = (const float*)d_in[11];
  const float* ob2  = (const float*)d_in[12];
  const float* mw1  = (const float*)d_in[13];
  const float* mb1  = (const float*)d_in[14];
  const float* mw2  = (const float*)d_in[15];
  const float* mb2  = (const float*)d_in[16];
  const float* mw3  = (const float*)d_in[17];
  const float* mb3  = (const float*)d_in[18];
  float* out = (float*)d_out;

  // ---- workspace carve (round-2-verified layout) ----
  char* base = (char*)d_ws;
  unsigned short* wTtw1 = (unsigned short*)base; base += 512 * 2560 * 2;
  unsigned short* wTtw2 = (unsigned short*)base; base += 512 * 2560 * 2;
  unsigned short* wTtw3 = (unsigned short*)base; base += 512 * 2560 * 2;
  unsigned short* wTow1 = (unsigned short*)base; base += 1024 * 1536 * 2;
  unsigned short* wTmw1 = (unsigned short*)base; base += 256 * 240 * 2;
  unsigned short* wTmw2 = (unsigned short*)base; base += 128 * 768 * 2;
  unsigned short* wTmw3 = (unsigned short*)base; base += 80 * 128 * 2;
  unsigned short* wTow2 = (unsigned short*)base; base += 80 * 1024 * 2;
  unsigned short* melsT = (unsigned short*)base; base += 16 * 4000 * 80 * 2;
  unsigned short* actA  = (unsigned short*)base; base += 16 * 4000 * 256 * 2;
  unsigned short* actB  = (unsigned short*)base; base += 16 * 4000 * 128 * 2;
  unsigned short* qb    = (unsigned short*)base; base += 16 * 4000 * 80 * 2;
  unsigned short* x0    = (unsigned short*)base; base += 16 * 512 * 512 * 2;
  unsigned short* x1    = (unsigned short*)base; base += 16 * 512 * 512 * 2;
  unsigned short* yb    = (unsigned short*)base; base += 16 * 512 * 1024 * 2;
  unsigned short* kb    = (unsigned short*)base; base += 16 * 512 * 80 * 2;
  float* q2v = (float*)base; base += 64000 * 4;
  float* k2v = (float*)base; base += 8192 * 4;

  // ---- weight convert/transpose (bf16) ----
  wcvt_k<<<5120, 256, 0, stream>>>(tw1, wTtw1, 512, 512, 5);
  wcvt_k<<<5120, 256, 0, stream>>>(tw2, wTtw2, 512, 512, 5);
  wcvt_k<<<5120, 256, 0, stream>>>(tw3, wTtw3, 512, 512, 5);
  wcvt_k<<<6144, 256, 0, stream>>>(ow1, wTow1, 1024, 512, 3);
  wcvt_k<<<240, 256, 0, stream>>>(mw1, wTmw1, 256, 80, 3);
  wcvt_k<<<384, 256, 0, stream>>>(mw2, wTmw2, 128, 256, 3);
  wcvt_k<<<40, 256, 0, stream>>>(mw3, wTmw3, 80, 128, 1);
  wcvt_k<<<320, 256, 0, stream>>>(ow2, wTow2, 80, 1024, 1);

  // ---- input conversions ----
  melscvt_k<<<dim3(63, 16), 256, 0, stream>>>(mels, melsT);
  gather_k<<<8192, 256, 0, stream>>>(ph, emb, x0);

  // ---- q path (T=4000), 64co x 128t tiles, 128-thread blocks ----
  conv_mfma<3, true ><<<dim3(32, 4, 16), 128, 0, stream>>>(melsT, wTmw1, mb1, actA,  80, 256, 4000);
  conv_mfma<3, true ><<<dim3(32, 2, 16), 128, 0, stream>>>(actA,  wTmw2, mb2, actB, 256, 128, 4000);
  conv_mfma<1, false><<<dim3(32, 2, 16), 128, 0, stream>>>(actB,  wTmw3, mb3, qb,   128,  80, 4000);

  // ---- k path (T=512) ----
  conv_mfma<5, true ><<<dim3(4,  8, 16), 128, 0, stream>>>(x0, wTtw1, tb1, x1,  512,  512, 512);
  conv_mfma<5, true ><<<dim3(4,  8, 16), 128, 0, stream>>>(x1, wTtw2, tb2, x0,  512,  512, 512);
  conv_mfma<5, true ><<<dim3(4,  8, 16), 128, 0, stream>>>(x0, wTtw3, tb3, x1,  512,  512, 512);
  conv_mfma<3, true ><<<dim3(4, 16, 16), 128, 0, stream>>>(x1, wTow1, ob1, yb,  512, 1024, 512);
  conv_mfma<1, false><<<dim3(4,  2, 16), 128, 0, stream>>>(yb, wTow2, ob2, kb, 1024,   80, 512);

  // ---- reductions + fused distance epilogue ----
  sumsq_k<<<250, 256, 0, stream>>>(qb, q2v, 64000);
  sumsq_k<<<32, 256, 0, stream>>>(kb, k2v, 8192);
  attn_mfma<<<dim3(8, 63, 16), 256, 0, stream>>>(qb, kb, q2v, k2v, out);
}

// Round 7
// 536.582 us; speedup vs baseline: 1.2997x; 1.0436x over previous
//
#include <hip/hip_runtime.h>

#define TEMP 0.0005f

typedef __attribute__((ext_vector_type(8))) short short8v;
typedef __attribute__((ext_vector_type(4))) float float4v;

static __device__ __forceinline__ unsigned short f2b(float f) {
  union { float f; unsigned int u; } x; x.f = f;
  unsigned int r = x.u + 0x7fffu + ((x.u >> 16) & 1u);
  return (unsigned short)(r >> 16);
}
static __device__ __forceinline__ float b2f(unsigned short h) {
  union { unsigned int u; float f; } x; x.u = ((unsigned int)h) << 16;
  return x.f;
}

static __device__ __forceinline__ void gload16(const void* g, void* l) {
  __builtin_amdgcn_global_load_lds(
      (const __attribute__((address_space(1))) void*)g,
      (__attribute__((address_space(3))) void*)l, 16, 0, 0);
}

// ---------------------------------------------------------------------------
// Weight convert+transpose+pad: w[Cout][Cin][K] f32 -> wT[CoutP][K][CinP] bf16
// zero-filled outside (Cout, Cin).  (round-3 verified math)
// ---------------------------------------------------------------------------
__global__ __launch_bounds__(256) void wcvt_k(
    const float* __restrict__ w, unsigned short* __restrict__ wT,
    int Cout, int Cin, int K, int CinP, int total)
{
  int o = blockIdx.x * 256 + threadIdx.x;
  if (o >= total) return;
  int co = o / (K * CinP);
  int rem = o - co * (K * CinP);
  int kh = rem / CinP;
  int ci = rem - kh * CinP;
  float v = (co < Cout && ci < Cin) ? w[((size_t)co * Cin + ci) * K + kh] : 0.f;
  wT[o] = f2b(v);
}

// ---------------------------------------------------------------------------
// Zero per-batch guard rows of a padded activation buffer [B][8+T+144][CinP]:
// rows [0,8) and [8+T, 8+T+8).
// ---------------------------------------------------------------------------
__global__ __launch_bounds__(256) void zp_k(
    unsigned short* __restrict__ p, int CinP, int T)
{
  int idx = blockIdx.x * 256 + threadIdx.x;
  int ci = idx % CinP;
  int r  = (idx / CinP) & 15;
  int b  = idx / (16 * CinP);
  int row = (r < 8) ? r : (8 + T + (r - 8));
  p[((size_t)b * (T + 152) + row) * CinP + ci] = 0;
}

// ---------------------------------------------------------------------------
// mels [16][80][4000] f32 -> melsT padded [16][8+4000+144][96] bf16
// (receives melsT BASE pointer; writes physical rows 8+t; cols 80..95 zero)
// ---------------------------------------------------------------------------
__global__ __launch_bounds__(256) void melscvt_k(
    const float* __restrict__ in, unsigned short* __restrict__ out)
{
  __shared__ float s[80][65];
  const int b  = blockIdx.y;
  const int t0 = blockIdx.x * 64;
  const int tid = threadIdx.x;
  for (int idx = tid; idx < 80 * 64; idx += 256) {
    int c = idx >> 6, tl = idx & 63;
    int t = t0 + tl;
    s[c][tl] = (t < 4000) ? in[((size_t)b * 80 + c) * 4000 + t] : 0.f;
  }
  __syncthreads();
  for (int idx = tid; idx < 64 * 96; idx += 256) {
    int tl = idx / 96, c = idx - tl * 96;
    int t = t0 + tl;
    if (t < 4000) {
      float v = (c < 80) ? s[c][tl] : 0.f;
      out[((size_t)b * 4152 + 8 + t) * 96 + c] = f2b(v);
    }
  }
}

// ---------------------------------------------------------------------------
// Embedding gather. Receives x0d DATA pointer (physical row 8): writes row s
// directly — NO internal +8 (round-3 bug fix).
// ---------------------------------------------------------------------------
__global__ __launch_bounds__(256) void gather_k(
    const int* __restrict__ ph, const float* __restrict__ emb,
    unsigned short* __restrict__ x)
{
  const int bs = blockIdx.x;            // b*512 + s
  const int b = bs >> 9, s = bs & 511;
  const int p = ph[bs];
  const float* e = emb + (size_t)p * 512;
  unsigned short* o = x + ((size_t)b * 664 + s) * 512;
  int i = threadIdx.x * 2;
  float2 v = *(const float2*)&e[i];
  unsigned int pk = (unsigned)f2b(v.x) | ((unsigned)f2b(v.y) << 16);
  *(unsigned int*)&o[i] = pk;
}

// ---------------------------------------------------------------------------
// MFMA conv1d (SAME, stride 1), bf16 in/out, fp32 accum.
// in: padded [B][.][CinP] bf16, DATA pointer (t=0 row = physical row 8);
//     rows [-8,0) and [T,T+8) are zero; rows beyond feed only discarded tiles.
// wT: [CoutP][K][CinP] bf16 (zero-padded).  out: [B][.][CoutP] data pointer.
// Block: 128 thr = 2 waves, tile 64co x 128t, wave 64co x 64t (4x4 acc).
// Staging: global_load_lds dwordx4 into linear LDS, dbuf, vmcnt(0)/chunk.
// ---------------------------------------------------------------------------
template<int K, bool RELU>
__global__ __launch_bounds__(128) void conv_g(
    const unsigned short* __restrict__ in,
    const unsigned short* __restrict__ wT,
    const float* __restrict__ bias,
    unsigned short* __restrict__ out,
    int CinP, int Cout, int CoutP, int T,
    long inBS, long outBS)
{
  constexpr int P      = K / 2;
  constexpr int NCH_IN = (128 + K - 1 + 15) / 16;   // 16-row (1024B) chunks
  constexpr int NCH_W  = K * 4;                     // 64-granule chunks

  __shared__ __align__(16) unsigned short in_s[2][NCH_IN * 16][32];
  __shared__ __align__(16) unsigned short w_s[2][K][64][32];

  const int b    = blockIdx.z;
  const int t0   = blockIdx.x * 128;
  const int co0  = blockIdx.y * 64;
  const int tid  = threadIdx.x;
  const int lane = tid & 63;
  const int wv   = tid >> 6;        // 0,1
  const int wt   = wv << 6;         // wave t-offset
  const int l15  = lane & 15;
  const int lq   = lane >> 4;       // 0..3

  const unsigned short* inb = in + (size_t)b * inBS;
  const int wrow = K * CinP;
  const int row_g = lane >> 2;      // staging row within 16-row chunk
  const int q_g   = lane & 3;

  float4v acc[4][4];
  #pragma unroll
  for (int m = 0; m < 4; ++m)
    #pragma unroll
    for (int n = 0; n < 4; ++n) { float4v z = {0.f,0.f,0.f,0.f}; acc[m][n] = z; }

  auto stage = [&](int buf, int ci0) {
    for (int ch = wv; ch < NCH_IN; ch += 2) {
      long t = (long)t0 + (ch * 16 + row_g) - P;
      gload16(inb + t * CinP + ci0 + q_g * 8, &in_s[buf][ch * 16][0]);
    }
    unsigned short* wdst = &w_s[buf][0][0][0];
    for (int ch = wv; ch < NCH_W; ch += 2) {
      int g = ch * 64 + lane;               // granule = kh*256 + co*4 + q
      int kh = g >> 8;
      int co = (g >> 2) & 63;
      int q  = g & 3;
      gload16(wT + (size_t)(co0 + co) * wrow + kh * CinP + ci0 + q * 8,
              wdst + ch * 512);
    }
  };

  auto compute = [&](int buf) {
    #pragma unroll
    for (int kh = 0; kh < K; ++kh) {
      short8v a0 = *(const short8v*)&w_s[buf][kh][     l15][lq * 8];
      short8v a1 = *(const short8v*)&w_s[buf][kh][16 + l15][lq * 8];
      short8v a2 = *(const short8v*)&w_s[buf][kh][32 + l15][lq * 8];
      short8v a3 = *(const short8v*)&w_s[buf][kh][48 + l15][lq * 8];
      short8v b0 = *(const short8v*)&in_s[buf][wt      + l15 + kh][lq * 8];
      short8v b1 = *(const short8v*)&in_s[buf][wt + 16 + l15 + kh][lq * 8];
      short8v b2 = *(const short8v*)&in_s[buf][wt + 32 + l15 + kh][lq * 8];
      short8v b3 = *(const short8v*)&in_s[buf][wt + 48 + l15 + kh][lq * 8];
      acc[0][0] = __builtin_amdgcn_mfma_f32_16x16x32_bf16(a0, b0, acc[0][0], 0, 0, 0);
      acc[0][1] = __builtin_amdgcn_mfma_f32_16x16x32_bf16(a0, b1, acc[0][1], 0, 0, 0);
      acc[0][2] = __builtin_amdgcn_mfma_f32_16x16x32_bf16(a0, b2, acc[0][2], 0, 0, 0);
      acc[0][3] = __builtin_amdgcn_mfma_f32_16x16x32_bf16(a0, b3, acc[0][3], 0, 0, 0);
      acc[1][0] = __builtin_amdgcn_mfma_f32_16x16x32_bf16(a1, b0, acc[1][0], 0, 0, 0);
      acc[1][1] = __builtin_amdgcn_mfma_f32_16x16x32_bf16(a1, b1, acc[1][1], 0, 0, 0);
      acc[1][2] = __builtin_amdgcn_mfma_f32_16x16x32_bf16(a1, b2, acc[1][2], 0, 0, 0);
      acc[1][3] = __builtin_amdgcn_mfma_f32_16x16x32_bf16(a1, b3, acc[1][3], 0, 0, 0);
      acc[2][0] = __builtin_amdgcn_mfma_f32_16x16x32_bf16(a2, b0, acc[2][0], 0, 0, 0);
      acc[2][1] = __builtin_amdgcn_mfma_f32_16x16x32_bf16(a2, b1, acc[2][1], 0, 0, 0);
      acc[2][2] = __builtin_amdgcn_mfma_f32_16x16x32_bf16(a2, b2, acc[2][2], 0, 0, 0);
      acc[2][3] = __builtin_amdgcn_mfma_f32_16x16x32_bf16(a2, b3, acc[2][3], 0, 0, 0);
      acc[3][0] = __builtin_amdgcn_mfma_f32_16x16x32_bf16(a3, b0, acc[3][0], 0, 0, 0);
      acc[3][1] = __builtin_amdgcn_mfma_f32_16x16x32_bf16(a3, b1, acc[3][1], 0, 0, 0);
      acc[3][2] = __builtin_amdgcn_mfma_f32_16x16x32_bf16(a3, b2, acc[3][2], 0, 0, 0);
      acc[3][3] = __builtin_amdgcn_mfma_f32_16x16x32_bf16(a3, b3, acc[3][3], 0, 0, 0);
    }
  };

  const int NC = CinP >> 5;
  stage(0, 0);
  asm volatile("s_waitcnt vmcnt(0)" ::: "memory");
  __syncthreads();
  int cur = 0;
  for (int c = 0; c < NC; ++c) {
    if (c + 1 < NC) stage(cur ^ 1, (c + 1) * 32);
    compute(cur);
    asm volatile("s_waitcnt vmcnt(0)" ::: "memory");
    __syncthreads();
    cur ^= 1;
  }

  // epilogue: D col = lane&15 -> t, row = (lane>>4)*4 + r -> co  (verified)
  unsigned short* outb = out + (size_t)b * outBS;
  #pragma unroll
  for (int m = 0; m < 4; ++m) {
    int co = co0 + m * 16 + (lq << 2);
    if (co >= Cout) continue;
    float4v bv = *(const float4v*)&bias[co];
    #pragma unroll
    for (int n = 0; n < 4; ++n) {
      int t = t0 + wt + n * 16 + l15;
      if (t >= T) continue;
      float v0 = acc[m][n][0] + bv[0];
      float v1 = acc[m][n][1] + bv[1];
      float v2 = acc[m][n][2] + bv[2];
      float v3 = acc[m][n][3] + bv[3];
      if (RELU) {
        v0 = fmaxf(v0, 0.f); v1 = fmaxf(v1, 0.f);
        v2 = fmaxf(v2, 0.f); v3 = fmaxf(v3, 0.f);
      }
      unsigned long long pk =
          (unsigned long long)((unsigned)f2b(v0) | ((unsigned)f2b(v1) << 16)) |
          ((unsigned long long)((unsigned)f2b(v2) | ((unsigned)f2b(v3) << 16)) << 32);
      *(unsigned long long*)&outb[(size_t)t * CoutP + co] = pk;
    }
  }
}

// ---------------------------------------------------------------------------
// attention[b][t][s] = -TEMP*(q2[t]+k2[s]-2*qk), MFMA over C=80 (pad 96).
// q2/k2 computed in-block from the staged LDS tiles (sumsq fusion).
// q: [16][4000][80] bf16, k: [16][512][80] bf16, out fp32 [16][4000][512].
// ---------------------------------------------------------------------------
__global__ __launch_bounds__(256) void attn_mfma(
    const unsigned short* __restrict__ q, const unsigned short* __restrict__ k,
    float* __restrict__ out)
{
  __shared__ unsigned short q_s[64][104];
  __shared__ unsigned short k_s[64][104];
  __shared__ float q2s[64];
  __shared__ float k2s[64];
  const int b  = blockIdx.z;
  const int t0 = blockIdx.y * 64;
  const int s0 = blockIdx.x * 64;
  const int tid  = threadIdx.x;
  const int lane = tid & 63;
  const int wv   = tid >> 6;
  const int wt   = (wv & 1) << 5;
  const int ws   = (wv >> 1) << 5;
  const int l15  = lane & 15;
  const int lq   = lane >> 4;

  for (int g = tid; g < 64 * 12; g += 256) {
    int row = g / 12, c = (g - row * 12) * 8;
    short8v vq = {}, vk = {};
    int t = t0 + row;
    if (c < 80) {
      if (t < 4000) vq = *(const short8v*)&q[((size_t)b * 4000 + t) * 80 + c];
      vk = *(const short8v*)&k[((size_t)b * 512 + s0 + row) * 80 + c];
    }
    *(short8v*)&q_s[row][c] = vq;
    *(short8v*)&k_s[row][c] = vk;
  }
  __syncthreads();

  // fused sum-of-squares (waves 0-1; waves 2-3 proceed straight to MFMA)
  if (tid < 128) {
    const unsigned short* rowp = (tid < 64) ? &q_s[tid][0] : &k_s[tid - 64][0];
    float s = 0.f;
    #pragma unroll
    for (int g = 0; g < 10; ++g) {
      short8v v = *(const short8v*)&rowp[g * 8];
      #pragma unroll
      for (int j = 0; j < 8; ++j) { float f = b2f((unsigned short)v[j]); s += f * f; }
    }
    if (tid < 64) q2s[tid] = s; else k2s[tid - 64] = s;
  }

  float4v acc[2][2];
  #pragma unroll
  for (int m = 0; m < 2; ++m)
    #pragma unroll
    for (int n = 0; n < 2; ++n) { float4v z = {0.f,0.f,0.f,0.f}; acc[m][n] = z; }

  #pragma unroll
  for (int ks = 0; ks < 3; ++ks) {
    short8v a0 = *(const short8v*)&q_s[wt      + l15][ks * 32 + lq * 8];
    short8v a1 = *(const short8v*)&q_s[wt + 16 + l15][ks * 32 + lq * 8];
    short8v b0 = *(const short8v*)&k_s[ws      + l15][ks * 32 + lq * 8];
    short8v b1 = *(const short8v*)&k_s[ws + 16 + l15][ks * 32 + lq * 8];
    acc[0][0] = __builtin_amdgcn_mfma_f32_16x16x32_bf16(a0, b0, acc[0][0], 0, 0, 0);
    acc[0][1] = __builtin_amdgcn_mfma_f32_16x16x32_bf16(a0, b1, acc[0][1], 0, 0, 0);
    acc[1][0] = __builtin_amdgcn_mfma_f32_16x16x32_bf16(a1, b0, acc[1][0], 0, 0, 0);
    acc[1][1] = __builtin_amdgcn_mfma_f32_16x16x32_bf16(a1, b1, acc[1][1], 0, 0, 0);
  }
  __syncthreads();   // q2s/k2s visible before epilogue

  #pragma unroll
  for (int m = 0; m < 2; ++m) {
    #pragma unroll
    for (int r = 0; r < 4; ++r) {
      int lt = wt + m * 16 + lq * 4 + r;
      int t = t0 + lt;
      if (t >= 4000) continue;
      float q2v = q2s[lt];
      #pragma unroll
      for (int n = 0; n < 2; ++n) {
        int ls = ws + n * 16 + l15;
        float v = -TEMP * (q2v + k2s[ls] - 2.f * acc[m][n][r]);
        out[((size_t)b * 4000 + t) * 512 + s0 + ls] = v;
      }
    }
  }
}

// ---------------------------------------------------------------------------
extern "C" void kernel_launch(void* const* d_in, const int* in_sizes, int n_in,
                              void* d_out, int out_size, void* d_ws, size_t ws_size,
                              hipStream_t stream)
{
  const float* mels = (const float*)d_in[0];
  const int*   ph   = (const int*)  d_in[1];
  const float* emb  = (const float*)d_in[2];
  const float* tw1  = (const float*)d_in[3];
  const float* tb1  = (const float*)d_in[4];
  const float* tw2  = (const float*)d_in[5];
  const float* tb2  = (const float*)d_in[6];
  const float* tw3  = (const float*)d_in[7];
  const float* tb3  = (const float*)d_in[8];
  const float* ow1  = (const float*)d_in[9];
  const float* ob1  = (const float*)d_in[10];
  const float* ow2  = (const float*)d_in[11];
  const float* ob2  = (const float*)d_in[12];
  const float* mw1  = (const float*)d_in[13];
  const float* mb1  = (const float*)d_in[14];
  const float* mw2  = (const float*)d_in[15];
  const float* mb2  = (const float*)d_in[16];
  const float* mw3  = (const float*)d_in[17];
  const float* mb3  = (const float*)d_in[18];
  float* out = (float*)d_out;

  // ---- workspace carve (padded weight buffers, padded activations) ----
  unsigned short* wsp = (unsigned short*)d_ws;
  unsigned short* wTtw1 = wsp; wsp += 512 * 5 * 512;
  unsigned short* wTtw2 = wsp; wsp += 512 * 5 * 512;
  unsigned short* wTtw3 = wsp; wsp += 512 * 5 * 512;
  unsigned short* wTow1 = wsp; wsp += 1024 * 3 * 512;
  unsigned short* wTmw1 = wsp; wsp += 256 * 3 * 96;
  unsigned short* wTmw2 = wsp; wsp += 128 * 3 * 256;
  unsigned short* wTmw3 = wsp; wsp += 128 * 1 * 128;
  unsigned short* wTow2 = wsp; wsp += 128 * 1 * 1024;
  unsigned short* melsT = wsp; wsp += (size_t)16 * 4152 * 96;
  unsigned short* ACT   = wsp; wsp += (size_t)16 * 4152 * 384;
  unsigned short* qb    = wsp; wsp += (size_t)16 * 4000 * 80;
  unsigned short* kb    = wsp; wsp += (size_t)16 * 512 * 80;

  unsigned short* actA = ACT;                                  // 16*4152*256
  unsigned short* actB = ACT + (size_t)16 * 4152 * 256;        // 16*4152*128
  unsigned short* x0   = ACT;                                  // 16*664*512
  unsigned short* x1   = ACT + (size_t)16 * 664 * 512;
  unsigned short* yb   = ACT + (size_t)2 * 16 * 664 * 512;     // 16*664*1024 (ends 21.76M < 25.51M)

  unsigned short* melsTd = melsT + 8 * 96;   const long melsBS = 4152 * 96;
  unsigned short* actAd  = actA + 8 * 256;   const long actABS = 4152 * 256;
  unsigned short* actBd  = actB + 8 * 128;   const long actBBS = 4152 * 128;
  unsigned short* x0d    = x0 + 8 * 512;     const long xBS    = 664 * 512;
  unsigned short* x1d    = x1 + 8 * 512;
  unsigned short* ybd    = yb + 8 * 1024;    const long yBS    = 664 * 1024;
  const long qBS = 4000 * 80, kBS = 512 * 80;

  // ---- weight convert (padded, kh-major) ----
  wcvt_k<<<5120, 256, 0, stream>>>(tw1, wTtw1, 512, 512, 5, 512, 512*5*512);
  wcvt_k<<<5120, 256, 0, stream>>>(tw2, wTtw2, 512, 512, 5, 512, 512*5*512);
  wcvt_k<<<5120, 256, 0, stream>>>(tw3, wTtw3, 512, 512, 5, 512, 512*5*512);
  wcvt_k<<<6144, 256, 0, stream>>>(ow1, wTow1, 1024, 512, 3, 512, 1024*3*512);
  wcvt_k<<<288,  256, 0, stream>>>(mw1, wTmw1, 256, 80, 3, 96, 256*3*96);
  wcvt_k<<<384,  256, 0, stream>>>(mw2, wTmw2, 128, 256, 3, 256, 128*3*256);
  wcvt_k<<<64,   256, 0, stream>>>(mw3, wTmw3, 80, 128, 1, 128, 128*1*128);
  wcvt_k<<<512,  256, 0, stream>>>(ow2, wTow2, 80, 1024, 1, 1024, 128*1*1024);

  // ---- q-path buffers: guards + convert ----
  zp_k<<< 96, 256, 0, stream>>>(melsT, 96, 4000);
  zp_k<<<256, 256, 0, stream>>>(actA, 256, 4000);
  zp_k<<<128, 256, 0, stream>>>(actB, 128, 4000);
  melscvt_k<<<dim3(63, 16), 256, 0, stream>>>(mels, melsT);

  // ---- q path (T=4000) ----
  conv_g<3, true ><<<dim3(32, 4, 16), 128, 0, stream>>>(melsTd, wTmw1, mb1, actAd,  96, 256, 256, 4000, melsBS, actABS);
  conv_g<3, true ><<<dim3(32, 2, 16), 128, 0, stream>>>(actAd,  wTmw2, mb2, actBd, 256, 128, 128, 4000, actABS, actBBS);
  conv_g<1, false><<<dim3(32, 2, 16), 128, 0, stream>>>(actBd,  wTmw3, mb3, qb,   128,  80,  80, 4000, actBBS, qBS);

  // ---- k-path buffers (reuse ACT region, q path done): guards + gather ----
  zp_k<<< 512, 256, 0, stream>>>(x0, 512, 512);
  zp_k<<< 512, 256, 0, stream>>>(x1, 512, 512);
  zp_k<<<1024, 256, 0, stream>>>(yb, 1024, 512);
  gather_k<<<8192, 256, 0, stream>>>(ph, emb, x0d);

  // ---- k path (T=512) ----
  conv_g<5, true ><<<dim3(4,  8, 16), 128, 0, stream>>>(x0d, wTtw1, tb1, x1d, 512,  512,  512, 512, xBS, xBS);
  conv_g<5, true ><<<dim3(4,  8, 16), 128, 0, stream>>>(x1d, wTtw2, tb2, x0d, 512,  512,  512, 512, xBS, xBS);
  conv_g<5, true ><<<dim3(4,  8, 16), 128, 0, stream>>>(x0d, wTtw3, tb3, x1d, 512,  512,  512, 512, xBS, xBS);
  conv_g<3, true ><<<dim3(4, 16, 16), 128, 0, stream>>>(x1d, wTow1, ob1, ybd, 512, 1024, 1024, 512, xBS, yBS);
  conv_g<1, false><<<dim3(4,  2, 16), 128, 0, stream>>>(ybd, wTow2, ob2, kb, 1024,   80,   80, 512, yBS, kBS);

  // ---- fused distance epilogue (q2/k2 computed in-block) ----
  attn_mfma<<<dim3(8, 63, 16), 256, 0, stream>>>(qb, kb, out);
}